// Round 14
// baseline (1167.407 us; speedup 1.0000x reference)
//
#include <hip/hip_runtime.h>
#include <hip/hip_bf16.h>
#include <math.h>

#define NT 1024
#define BSZ 128
#define TSTEPS 32
#define DIN 128
#define DHH 128
#define NSLOT 512
#define EPSF 1e-8f

// LDS: [0,131072) mem bf16[512][128] XOR-swizzled; then float scratch F[7160]
static constexpr int F_FLOATS = 7160;
static constexpr size_t LDS_BYTES = 131072 + F_FLOATS * sizeof(float);

__device__ __forceinline__ float bf_lo(unsigned u) {
  union { unsigned u; float f; } c; c.u = u << 16; return c.f;
}
__device__ __forceinline__ float bf_hi(unsigned u) {
  union { unsigned u; float f; } c; c.u = u & 0xffff0000u; return c.f;
}
__device__ __forceinline__ unsigned short f2us(float f) {
  union { unsigned short s; __hip_bfloat16 h; } c; c.h = __float2bfloat16(f); return c.s;
}
__device__ __forceinline__ unsigned pkbf(float a, float b) {
  union { __hip_bfloat162 h2; unsigned u; } c;
  c.h2 = __float22bfloat162_rn(make_float2(a, b));
  return c.u;
}
__device__ __forceinline__ float sigmoid_(float x) { return 1.0f / (1.0f + __expf(-x)); }
__device__ __forceinline__ float softplus_(float x) {
  return fmaxf(x, 0.0f) + log1pf(__expf(-fabsf(x)));
}
__device__ __forceinline__ float tanh_(float x) {
  float e = __expf(-2.0f * fabsf(x));
  float t = (1.0f - e) / (1.0f + e);
  return copysignf(t, x);
}
__device__ __forceinline__ float waveSum(float v) {
#pragma unroll
  for (int m = 32; m >= 1; m >>= 1) v += __shfl_xor(v, m);
  return v;
}

// One block (1024 threads) per batch element; all 32 steps in-block.
// mem in LDS, rows XOR-swizzled: stored uint4 slot u = c ^ ((n>>2)&3).
// Base = r13 (841us). Deltas:
//   1. Seg 4+5 fused (producer==consumer thread map; head scalars from U).
//   2. Key packing dropped: Seg 6 reads f32 keys (b128 broadcast).
//   3. Phase H spread: x@Wxh in Seg-11-upper (->sP1), h@Whh in Seg-8-upper
//      (->U[2048..2559]); Seg 1 = r@Wrh only. t=0 peeled. sP-zero in Seg 3.
__global__ __launch_bounds__(NT, 4)
void ntm_kernel(const float* __restrict__ x,
                const float* __restrict__ Wxh,
                const float* __restrict__ Whh,
                const float* __restrict__ Wrh,
                const float* __restrict__ bh,
                const float* __restrict__ Wout,
                const float* __restrict__ bout,
                const float* __restrict__ Wr,
                const float* __restrict__ br,
                const float* __restrict__ Ww,
                const float* __restrict__ bw,
                float* __restrict__ out)
{
  extern __shared__ char smem[];
  uint4* memv = (uint4*)smem;              // bf16 mem, row n = 16 uint4 (swizzled)
  float* F = (float*)(smem + 131072);

  const int b = blockIdx.x;
  const int tid = threadIdx.x;
  const int g = tid >> 4, l = tid & 15;    // Phase-B mapping
  const int lane = tid & 63, wid = tid >> 6;

  float* U      = F + 0;      // 2560: Seg1 rWrh partials [0..2047]; Seg3 O-partials;
                              //       eR[0..511], eW[512..1023]; p2raw[0..511];
                              //       Whh partials [2048..2559]
  float* yP     = F + 2560;   // 2048 Y partials
  float* sWprev = F + 4608;   // 512
  float* sWr    = F + 5120;   // 512
  float* sP1    = F + 5632;   // 512: xW partials (Seg11-upper) then p1 (Seg7/8)
  float* sOr    = F + 6144;   // 144 (134 used; only [0..127] live past SegF)
  float* sOw    = F + 6288;   // 392: [0..127] k_w, [136..263] e, [264..391] a
  float* sH     = F + 6680;   // 128
  float* sR     = F + 6808;   // 128 (ds_add target in Seg 9)
  float* sXt    = F + 6936;   // 128
  float* sP     = F + 7064;   // 96: [0]kr2 [1]kw2 [2]SR [3]SW [4]P1 [5]P2; [80..91] scalars
  float* eR     = U + 0;
  float* eW     = U + 512;

  // ---- init ----
  {
    const unsigned short mb = f2us(1e-6f);
    const unsigned w32 = ((unsigned)mb << 16) | mb;
    const uint4 fv = make_uint4(w32, w32, w32, w32);
    for (int i = tid; i < NSLOT * DHH / 8; i += NT) memv[i] = fv;
  }
  for (int i = tid; i < NSLOT; i += NT) sWprev[i] = 1.0f / NSLOT;
  if (tid < DHH) { sH[tid] = 0.0f; sR[tid] = 0.0f; }
  if (tid < DIN) sXt[tid] = x[(size_t)b * TSTEPS * DIN + tid];
  if (tid < 512) U[2048 + tid] = 0.0f;     // Whh partials zero for t=0
  __syncthreads();
  // ---- pre-loop: xW(0) partials into sP1 ----
  if (tid >= 512) {
    const int p = tid - 512;
    const int c = p & 127, s = p >> 7;
    const int i0 = s * 32;
    float acc = 0.0f;
#pragma unroll 8
    for (int w = 0; w < 32; ++w) acc += sXt[i0 + w] * Wxh[(i0 + w) * DHH + c];
    sP1[s * 128 + c] = acc;
  }
  __syncthreads();

  for (int t = 0; t < TSTEPS; ++t) {
    // ==== Seg 1: r@Wrh partials (8 f2/thread) + y-finalize(t-1) ====
    {
      if (t > 0 && tid < DIN) {
        float y = bout[tid];
#pragma unroll
        for (int q = 0; q < 16; ++q) y += yP[q * 128 + tid];
        out[((size_t)b * TSTEPS + (t - 1)) * DIN + tid] = y;
      }
      const int q = tid & 63, s = tid >> 6;
      const int j2 = q * 2, i0 = s * 8;
      float2 acc = make_float2(0.f, 0.f);
#pragma unroll
      for (int w = 0; w < 8; ++w) {
        const int i = i0 + w;
        const float v = sR[i];
        const float2 wv = *(const float2*)(Wrh + i * DHH + j2);
        acc.x = fmaf(v, wv.x, acc.x);
        acc.y = fmaf(v, wv.y, acc.y);
      }
      *(float2*)(U + s * 128 + j2) = acc;
      __syncthreads();
    }
    // ==== Seg 2: h = tanh(bh + rWrh(16) + xW(4) + hWhh(4)) ====
    if (tid < DHH) {
      float a2 = bh[tid];
#pragma unroll
      for (int q2 = 0; q2 < 16; ++q2) a2 += U[q2 * 128 + tid];
#pragma unroll
      for (int q2 = 0; q2 < 4; ++q2) a2 += sP1[q2 * 128 + tid];
#pragma unroll
      for (int q2 = 0; q2 < 4; ++q2) a2 += U[2048 + q2 * 128 + tid];
      sH[tid] = tanh_(a2);
    }
    __syncthreads();

    // ==== Seg 3: O partials — 262 col-pairs x 4 row-quarters; + sP zeroing ====
    {
#pragma unroll
      for (int k = 0; k < 2; ++k) {
        const int s = tid + k * NT;
        if (s < 1048) {
          const int q = (s >= 786) ? 3 : (s >= 524) ? 2 : (s >= 262) ? 1 : 0;
          const int P = s - 262 * q;
          const int i0 = 32 * q;
          const float2* p;
          int strideF2;
          if (P < 67) { p = (const float2*)(Wr + i0 * 134 + 2 * P); strideF2 = 67; }
          else        { p = (const float2*)(Ww + i0 * 390 + 2 * (P - 67)); strideF2 = 195; }
          float2 acc = make_float2(0.f, 0.f);
#pragma unroll 8
          for (int w = 0; w < 32; ++w) {
            const float v = sH[i0 + w];
            const float2 wv = *p;
            acc.x = fmaf(v, wv.x, acc.x);
            acc.y = fmaf(v, wv.y, acc.y);
            p += strideF2;
          }
          *(float2*)(U + s * 2) = acc;
        }
      }
      if (tid == 1023) {
        sP[0] = 0.f; sP[1] = 0.f; sP[2] = 0.f; sP[3] = 0.f; sP[4] = 0.f; sP[5] = 0.f;
      }
      __syncthreads();
    }

    // ==== Seg F (fused combine + transforms + knorm + head scalars) ====
    // producer==consumer mapping; sR zeroed here too (tids 640..767).
    {
      if (tid < 134) {                      // o_r col tid
        float v = 0.f;
#pragma unroll
        for (int q = 0; q < 4; ++q) v += U[tid + 524 * q];
        v += br[tid];
        sOr[tid] = v;
        if (tid < 128) {                    // waves 0,1 whole
          float s2 = waveSum(v * v);
          if (lane == 0) atomicAdd(&sP[0], s2);
        }
      } else if (tid == 134) {              // read-head scalars from U directly
        float sc[6];
#pragma unroll
        for (int j = 0; j < 6; ++j) {
          float v = 0.f;
#pragma unroll
          for (int q = 0; q < 4; ++q) v += U[(128 + j) + 524 * q];
          sc[j] = v + br[128 + j];
        }
        sP[80] = softplus_(sc[0]);
        sP[81] = sigmoid_(sc[1]);
        float mx = fmaxf(sc[2], fmaxf(sc[3], sc[4]));
        float e0 = __expf(sc[2] - mx), e1 = __expf(sc[3] - mx), e2 = __expf(sc[4] - mx);
        float es = e0 + e1 + e2;
        sP[82] = e0 / es; sP[83] = e1 / es; sP[84] = e2 / es;
        sP[85] = 1.0f + softplus_(sc[5]);
      } else if (tid == 135) {              // write-head scalars (o_w cols 128..133)
        float sc[6];
#pragma unroll
        for (int j = 0; j < 6; ++j) {
          float v = 0.f;
#pragma unroll
          for (int q = 0; q < 4; ++q) v += U[(262 + j) + 524 * q];
          sc[j] = v + bw[128 + j];
        }
        sP[86] = softplus_(sc[0]);
        sP[87] = sigmoid_(sc[1]);
        float mx = fmaxf(sc[2], fmaxf(sc[3], sc[4]));
        float e0 = __expf(sc[2] - mx), e1 = __expf(sc[3] - mx), e2 = __expf(sc[4] - mx);
        float es = e0 + e1 + e2;
        sP[88] = e0 / es; sP[89] = e1 / es; sP[90] = e2 / es;
        sP[91] = 1.0f + softplus_(sc[5]);
      } else if (tid >= 256 && tid < 512) { // e (256..383) / a (384..511): col cw=tid-122
        const int cc = tid + 12;            // combined col 134+cw
        float v = 0.f;
#pragma unroll
        for (int q = 0; q < 4; ++q) v += U[cc + 524 * q];
        v += bw[tid - 122];
        sOw[tid - 120] = (tid < 384) ? sigmoid_(v) : tanh_(v);
      } else if (tid >= 512 && tid < 640) { // k_w col cw=tid-512 (waves 8,9 whole)
        const int cw = tid - 512;
        float v = 0.f;
#pragma unroll
        for (int q = 0; q < 4; ++q) v += U[(134 + cw) + 524 * q];
        v += bw[cw];
        sOw[cw] = v;
        float s2 = waveSum(v * v);
        if (lane == 0) atomicAdd(&sP[1], s2);
      } else if (tid >= 640 && tid < 768) {
        sR[tid - 640] = 0.f;                // Seg-9 ds_add target
      }
      __syncthreads();
    }

    // ==== Seg 6 (A): dots + norm + exp fused; f32 keys; SR/SW via atomic ====
    {
      const float kn_r = sqrtf(sP[0]);
      const float kn_w = sqrtf(sP[1]);
      const float beta_r = sP[80], beta_w = sP[86];
      const int n = tid >> 1, hf = tid & 1;
      const int sw = (n >> 2) & 3;
      float dr = 0.f, dw = 0.f, ss = 0.f;
#pragma unroll
      for (int c = 0; c < 8; ++c) {
        const int cl = hf * 8 + c;
        const uint4 mv = memv[n * 16 + (cl ^ sw)];
        const float4 kra = *(const float4*)(sOr + cl * 8);
        const float4 krb = *(const float4*)(sOr + cl * 8 + 4);
        const float4 kwa = *(const float4*)(sOw + cl * 8);
        const float4 kwb = *(const float4*)(sOw + cl * 8 + 4);
        const unsigned mw_[4] = { mv.x, mv.y, mv.z, mv.w };
        const float krf[8] = { kra.x, kra.y, kra.z, kra.w, krb.x, krb.y, krb.z, krb.w };
        const float kwf[8] = { kwa.x, kwa.y, kwa.z, kwa.w, kwb.x, kwb.y, kwb.z, kwb.w };
#pragma unroll
        for (int j = 0; j < 4; ++j) {
          const float m0 = bf_lo(mw_[j]), m1 = bf_hi(mw_[j]);
          dr = fmaf(m0, krf[2 * j], dr); dr = fmaf(m1, krf[2 * j + 1], dr);
          dw = fmaf(m0, kwf[2 * j], dw); dw = fmaf(m1, kwf[2 * j + 1], dw);
          ss = fmaf(m0, m0, ss);         ss = fmaf(m1, m1, ss);
        }
      }
      dr += __shfl_xor(dr, 1);
      dw += __shfl_xor(dw, 1);
      ss += __shfl_xor(ss, 1);
      const float nr = sqrtf(ss);
      const float er = __expf(beta_r * dr / (nr * kn_r + EPSF));
      const float ew = __expf(beta_w * dw / (nr * kn_w + EPSF));
      if (hf == 0) { eR[n] = er; eW[n] = ew; }
      float s1 = waveSum(er) * 0.5f;
      float s2 = waveSum(ew) * 0.5f;
      if (lane == 0) { atomicAdd(&sP[2], s1); atomicAdd(&sP[3], s2); }
      __syncthreads();
    }

    // ==== Seg 7: alpha (tid<512) + Y-top GEMV rows 0..127 (upper waves) ====
    {
      if (tid < NSLOT) {
        const float invE = 1.0f / sP[2];
        const float gr = sP[81], omg = 1.0f - sP[81];
        const int im = (tid - 1) & 511, ip = (tid + 1) & 511;
        const float wgm = gr * (eR[im] * invE) + omg * sWprev[im];
        const float wg0 = gr * (eR[tid] * invE) + omg * sWprev[tid];
        const float wgp = gr * (eR[ip] * invE) + omg * sWprev[ip];
        const float wt = sP[82] * wgp + sP[83] * wg0 + sP[84] * wgm;
        float p1 = (wt > 0.0f) ? __expf(sP[85] * __logf(wt)) : 0.0f;
        float P = waveSum(p1);
        sP1[tid] = p1;
        if (lane == 0) atomicAdd(&sP[4], P);
      } else {
        const int p = tid - 512;
        const int j4 = (p & 31) * 4, sl = p >> 5;
        float4 acc = make_float4(0.f, 0.f, 0.f, 0.f);
#pragma unroll
        for (int w = 0; w < 8; ++w) {
          const float v = sH[8 * sl + w];
          const float4 wv = *(const float4*)(Wout + (8 * sl + w) * DIN + j4);
          acc.x = fmaf(v, wv.x, acc.x); acc.y = fmaf(v, wv.y, acc.y);
          acc.z = fmaf(v, wv.z, acc.z); acc.w = fmaf(v, wv.w, acc.w);
        }
        *(float4*)(yP + sl * 128 + j4) = acc;
      }
      __syncthreads();
    }
    // ==== Seg 8: beta (tid<512) + Whh partials (512..767) + x prefetch (896+) ====
    {
      if (tid < NSLOT) {
        const float pinv1 = 1.0f / (sP[4] + EPSF);
        const float invE = 1.0f / sP[3];
        const float gw = sP[87], omg = 1.0f - sP[87];
        const int im = (tid - 1) & 511, ip = (tid + 1) & 511;
        const float wgm = gw * (eW[im] * invE) + omg * (sP1[im] * pinv1);
        const float wg0 = gw * (eW[tid] * invE) + omg * (sP1[tid] * pinv1);
        const float wgp = gw * (eW[ip] * invE) + omg * (sP1[ip] * pinv1);
        sWr[tid] = sP1[tid] * pinv1;
        const float wt = sP[88] * wgp + sP[89] * wg0 + sP[90] * wgm;
        float p2 = (wt > 0.0f) ? __expf(sP[91] * __logf(wt)) : 0.0f;
        float P = waveSum(p2);
        U[tid] = p2;                       // raw p2 (eR region, dead)
        if (lane == 0) atomicAdd(&sP[5], P);
      } else if (tid < 768) {              // h@Whh partials for next step
        const int p = tid - 512;
        const int qp = p & 63, s = p >> 6;
        const int j2 = qp * 2, i0 = s * 32;
        float2 acc = make_float2(0.f, 0.f);
#pragma unroll 8
        for (int w = 0; w < 32; ++w) {
          const float v = sH[i0 + w];
          const float2 wv = *(const float2*)(Whh + (i0 + w) * DHH + j2);
          acc.x = fmaf(v, wv.x, acc.x);
          acc.y = fmaf(v, wv.y, acc.y);
        }
        *(float2*)(U + 2048 + s * 128 + j2) = acc;
      } else if (tid >= 896 && t + 1 < TSTEPS) {
        const int i = tid - 896;
        sXt[i] = x[((size_t)b * TSTEPS + (t + 1)) * DIN + i];
      }
      __syncthreads();
    }

    // ==== Seg 9 (B): w_w inline; r-sweep + mem update; r via ds_add into sR ====
    {
      const float pinv2 = 1.0f / (sP[5] + EPSF);
      if (tid < NSLOT) sWprev[tid] = U[tid] * pinv2;   // next step's w_prev

      const int cl = l ^ ((g >> 2) & 3);
      float4 e4a = *(const float4*)(sOw + 136 + cl * 8);
      float4 e4b = *(const float4*)(sOw + 140 + cl * 8);
      float4 a4a = *(const float4*)(sOw + 264 + cl * 8);
      float4 a4b = *(const float4*)(sOw + 268 + cl * 8);
      const float e8[8] = { e4a.x, e4a.y, e4a.z, e4a.w, e4b.x, e4b.y, e4b.z, e4b.w };
      const float a8[8] = { a4a.x, a4a.y, a4a.z, a4a.w, a4b.x, a4b.y, a4b.z, a4b.w };
      float r8[8] = { 0, 0, 0, 0, 0, 0, 0, 0 };
#pragma unroll 2
      for (int it = 0; it < 8; ++it) {
        const int n = g + 64 * it;
        const float wrn = sWr[n];
        const float wwn = U[n] * pinv2;
        uint4 pk = memv[n * 16 + l];
        const unsigned wds[4] = { pk.x, pk.y, pk.z, pk.w };
        float m[8];
#pragma unroll
        for (int j = 0; j < 4; ++j) { m[2 * j] = bf_lo(wds[j]); m[2 * j + 1] = bf_hi(wds[j]); }
#pragma unroll
        for (int j = 0; j < 8; ++j) {
          r8[j] = fmaf(wrn, m[j], r8[j]);
          const float d = fmaf(-e8[j], m[j], a8[j]);
          m[j] = fmaf(wwn, d, m[j]);
        }
        pk.x = pkbf(m[0], m[1]);
        pk.y = pkbf(m[2], m[3]);
        pk.z = pkbf(m[4], m[5]);
        pk.w = pkbf(m[6], m[7]);
        memv[n * 16 + l] = pk;
      }
#pragma unroll
      for (int j = 0; j < 8; ++j) {
        r8[j] += __shfl_xor(r8[j], 16);
        r8[j] += __shfl_xor(r8[j], 32);
      }
      if (lane < 16) {
#pragma unroll
        for (int j = 0; j < 8; ++j) atomicAdd(&sR[cl * 8 + j], r8[j]);
      }
      __syncthreads();
    }

    // ==== Seg 11: Y-bottom (tid<512) + xW(t+1) partials (upper -> sP1) ====
    {
      if (tid < 512) {
        const int j4 = (tid & 31) * 4, sl = tid >> 5;
        float4 acc = *(const float4*)(yP + sl * 128 + j4);
#pragma unroll
        for (int w = 0; w < 8; ++w) {
          const float v = sR[8 * sl + w];
          const float4 wv = *(const float4*)(Wout + (128 + 8 * sl + w) * DIN + j4);
          acc.x = fmaf(v, wv.x, acc.x); acc.y = fmaf(v, wv.y, acc.y);
          acc.z = fmaf(v, wv.z, acc.z); acc.w = fmaf(v, wv.w, acc.w);
        }
        *(float4*)(yP + sl * 128 + j4) = acc;
      } else {
        const int p = tid - 512;
        const int c = p & 127, s = p >> 7;
        const int i0 = s * 32;
        float acc = 0.0f;
#pragma unroll 8
        for (int w = 0; w < 32; ++w) acc += sXt[i0 + w] * Wxh[(i0 + w) * DHH + c];
        sP1[s * 128 + c] = acc;
      }
      __syncthreads();
    }
  }

  // final y
  if (tid < DIN) {
    float y = bout[tid];
#pragma unroll
    for (int q = 0; q < 16; ++q) y += yP[q * 128 + tid];
    out[((size_t)b * TSTEPS + (TSTEPS - 1)) * DIN + tid] = y;
  }
}

extern "C" void kernel_launch(void* const* d_in, const int* in_sizes, int n_in,
                              void* d_out, int out_size, void* d_ws, size_t ws_size,
                              hipStream_t stream) {
  (void)in_sizes; (void)n_in; (void)out_size; (void)d_ws; (void)ws_size;
  hipFuncSetAttribute(reinterpret_cast<const void*>(ntm_kernel),
                      hipFuncAttributeMaxDynamicSharedMemorySize, (int)LDS_BYTES);
  ntm_kernel<<<dim3(BSZ), dim3(NT), LDS_BYTES, stream>>>(
      (const float*)d_in[0], (const float*)d_in[1], (const float*)d_in[2],
      (const float*)d_in[3], (const float*)d_in[4], (const float*)d_in[5],
      (const float*)d_in[6], (const float*)d_in[7], (const float*)d_in[8],
      (const float*)d_in[9], (const float*)d_in[10],
      (float*)d_out);
}

// Round 15
// 872.457 us; speedup vs baseline: 1.3381x; 1.3381x over previous
//
#include <hip/hip_runtime.h>
#include <hip/hip_bf16.h>
#include <math.h>

#define NT 1024
#define BSZ 128
#define TSTEPS 32
#define DIN 128
#define DHH 128
#define NSLOT 512
#define EPSF 1e-8f

// LDS: [0,131072) mem bf16[512][128] XOR-swizzled; then float scratch F[7160]
static constexpr int F_FLOATS = 7160;
static constexpr size_t LDS_BYTES = 131072 + F_FLOATS * sizeof(float);

__device__ __forceinline__ float bf_lo(unsigned u) {
  union { unsigned u; float f; } c; c.u = u << 16; return c.f;
}
__device__ __forceinline__ float bf_hi(unsigned u) {
  union { unsigned u; float f; } c; c.u = u & 0xffff0000u; return c.f;
}
__device__ __forceinline__ unsigned short f2us(float f) {
  union { unsigned short s; __hip_bfloat16 h; } c; c.h = __float2bfloat16(f); return c.s;
}
__device__ __forceinline__ unsigned pkbf(float a, float b) {
  union { __hip_bfloat162 h2; unsigned u; } c;
  c.h2 = __float22bfloat162_rn(make_float2(a, b));
  return c.u;
}
__device__ __forceinline__ float sigmoid_(float x) { return 1.0f / (1.0f + __expf(-x)); }
__device__ __forceinline__ float softplus_(float x) {
  return fmaxf(x, 0.0f) + log1pf(__expf(-fabsf(x)));
}
__device__ __forceinline__ float tanh_(float x) {
  float e = __expf(-2.0f * fabsf(x));
  float t = (1.0f - e) / (1.0f + e);
  return copysignf(t, x);
}
__device__ __forceinline__ float waveSum(float v) {
#pragma unroll
  for (int m = 32; m >= 1; m >>= 1) v += __shfl_xor(v, m);
  return v;
}

// One block (1024 threads) per batch element; all 32 steps in-block.
// mem in LDS, rows XOR-swizzled: stored uint4 slot u = c ^ ((n>>2)&3).
// Base = r13 (841us verified). SINGLE delta: Seg 4+5 fused into SegF
// (producer==consumer map; head scalars + key packing read U directly;
// sP zeroing moved to Seg 3 tail; sR zeroing inside SegF). Everything
// else byte-identical to r13. (r14's f32-keys and H-spread reverted —
// counter-convicted of conflict/L2 regressions.)
__global__ __launch_bounds__(NT, 4)
void ntm_kernel(const float* __restrict__ x,
                const float* __restrict__ Wxh,
                const float* __restrict__ Whh,
                const float* __restrict__ Wrh,
                const float* __restrict__ bh,
                const float* __restrict__ Wout,
                const float* __restrict__ bout,
                const float* __restrict__ Wr,
                const float* __restrict__ br,
                const float* __restrict__ Ww,
                const float* __restrict__ bw,
                float* __restrict__ out)
{
  extern __shared__ char smem[];
  uint4* memv = (uint4*)smem;              // bf16 mem, row n = 16 uint4 (swizzled)
  float* F = (float*)(smem + 131072);

  const int b = blockIdx.x;
  const int tid = threadIdx.x;
  const int g = tid >> 4, l = tid & 15;    // Phase-B mapping
  const int lane = tid & 63, wid = tid >> 6;

  float* U      = F + 0;      // 2560 multi-use: O/H partials; eR[0..511], eW[512..1023];
                              //      p2raw[0..511]
  float* yP     = F + 2560;   // 2048 Y partials (live across step boundary)
  float* sWprev = F + 4608;   // 512
  float* sWr    = F + 5120;   // 512
  float* sP1    = F + 5632;   // 512 p1; aliased early by krP/kwP packed keys
  float* sOr    = F + 6144;   // 144 (134 used)
  float* sOw    = F + 6288;   // 392: [0..127] k_w, [136..263] e (16B-aligned), [264..391] a
  float* sH     = F + 6680;   // 128
  float* sR     = F + 6808;   // 128 (ds_add target in Seg 9)
  float* sXt    = F + 6936;   // 128
  float* sP     = F + 7064;   // 96: [0]kr2 [1]kw2 [2]SR [3]SW [4]P1 [5]P2; [80..91] scalars
  uint4* krP    = (uint4*)(sP1 + 0);
  uint4* kwP    = (uint4*)(sP1 + 64);
  float* eR     = U + 0;
  float* eW     = U + 512;

  // ---- init ----
  {
    const unsigned short mb = f2us(1e-6f);
    const unsigned w32 = ((unsigned)mb << 16) | mb;
    const uint4 fv = make_uint4(w32, w32, w32, w32);
    for (int i = tid; i < NSLOT * DHH / 8; i += NT) memv[i] = fv;
  }
  for (int i = tid; i < NSLOT; i += NT) sWprev[i] = 1.0f / NSLOT;
  if (tid < DHH) { sH[tid] = 0.0f; sR[tid] = 0.0f; }
  if (tid < DIN) sXt[tid] = x[(size_t)b * TSTEPS * DIN + tid];
  __syncthreads();

  for (int t = 0; t < TSTEPS; ++t) {
    // ==== Seg 1: H partials (float2 weights, LDS state reads) + y-finalize(t-1) ====
    {
      if (t > 0 && tid < DIN) {
        float y = bout[tid];
#pragma unroll
        for (int q = 0; q < 16; ++q) y += yP[q * 128 + tid];
        out[((size_t)b * TSTEPS + (t - 1)) * DIN + tid] = y;
      }
      const int q = tid & 63, s = tid >> 6;   // s == wid: wave-uniform rows
      const int j2 = q * 2, i0 = s * 24;
      float2 acc = make_float2(0.f, 0.f);
#pragma unroll 8
      for (int w = 0; w < 24; ++w) {
        const int i = i0 + w;
        float v; const float* Wp;
        if (i < 128)      { v = sXt[i];       Wp = Wxh + i * DHH; }
        else if (i < 256) { v = sH[i - 128];  Wp = Whh + (i - 128) * DHH; }
        else              { v = sR[i - 256];  Wp = Wrh + (i - 256) * DHH; }
        const float2 wv = *(const float2*)(Wp + j2);
        acc.x = fmaf(v, wv.x, acc.x);
        acc.y = fmaf(v, wv.y, acc.y);
      }
      *(float2*)(U + s * 128 + j2) = acc;
      __syncthreads();
    }
    // ==== Seg 2: h = tanh(sum + bh) ====
    if (tid < DHH) {
      float a2 = bh[tid];
#pragma unroll
      for (int q2 = 0; q2 < 16; ++q2) a2 += U[q2 * 128 + tid];
      sH[tid] = tanh_(a2);
    }
    __syncthreads();

    // ==== Seg 3: O partials — 262 col-pairs x 4 row-quarters + sP zeroing ====
    {
#pragma unroll
      for (int k = 0; k < 2; ++k) {
        const int s = tid + k * NT;
        if (s < 1048) {
          const int q = (s >= 786) ? 3 : (s >= 524) ? 2 : (s >= 262) ? 1 : 0;
          const int P = s - 262 * q;
          const int i0 = 32 * q;
          const float2* p;
          int strideF2;
          if (P < 67) { p = (const float2*)(Wr + i0 * 134 + 2 * P); strideF2 = 67; }
          else        { p = (const float2*)(Ww + i0 * 390 + 2 * (P - 67)); strideF2 = 195; }
          float2 acc = make_float2(0.f, 0.f);
#pragma unroll 8
          for (int w = 0; w < 32; ++w) {
            const float v = sH[i0 + w];
            const float2 wv = *p;
            acc.x = fmaf(v, wv.x, acc.x);
            acc.y = fmaf(v, wv.y, acc.y);
            p += strideF2;
          }
          *(float2*)(U + s * 2) = acc;
        }
      }
      if (tid == 1023) {
        sP[0] = 0.f; sP[1] = 0.f; sP[2] = 0.f; sP[3] = 0.f; sP[4] = 0.f; sP[5] = 0.f;
      }
      __syncthreads();
    }

    // ==== Seg F: fused combine+bias / knorm / e,a transforms / key packing /
    //      head scalars / sR zeroing — producer==consumer thread map ====
    {
      if (tid < 134) {                      // o_r col tid
        float v = 0.f;
#pragma unroll
        for (int q = 0; q < 4; ++q) v += U[tid + 524 * q];
        v += br[tid];
        sOr[tid] = v;
        if (tid < 128) {                    // waves 0,1 whole: |k_r|^2
          float s2 = waveSum(v * v);
          if (lane == 0) atomicAdd(&sP[0], s2);
        }
      } else if (tid == 134) {              // read-head scalars from U directly
        float sc[6];
#pragma unroll
        for (int j = 0; j < 6; ++j) {
          float v = 0.f;
#pragma unroll
          for (int q = 0; q < 4; ++q) v += U[(128 + j) + 524 * q];
          sc[j] = v + br[128 + j];
        }
        sP[80] = softplus_(sc[0]);
        sP[81] = sigmoid_(sc[1]);
        float mx = fmaxf(sc[2], fmaxf(sc[3], sc[4]));
        float e0 = __expf(sc[2] - mx), e1 = __expf(sc[3] - mx), e2 = __expf(sc[4] - mx);
        float es = e0 + e1 + e2;
        sP[82] = e0 / es; sP[83] = e1 / es; sP[84] = e2 / es;
        sP[85] = 1.0f + softplus_(sc[5]);
      } else if (tid == 135) {              // write-head scalars (o_w cols 128..133)
        float sc[6];
#pragma unroll
        for (int j = 0; j < 6; ++j) {
          float v = 0.f;
#pragma unroll
          for (int q = 0; q < 4; ++q) v += U[(262 + j) + 524 * q];
          sc[j] = v + bw[128 + j];
        }
        sP[86] = softplus_(sc[0]);
        sP[87] = sigmoid_(sc[1]);
        float mx = fmaxf(sc[2], fmaxf(sc[3], sc[4]));
        float e0 = __expf(sc[2] - mx), e1 = __expf(sc[3] - mx), e2 = __expf(sc[4] - mx);
        float es = e0 + e1 + e2;
        sP[88] = e0 / es; sP[89] = e1 / es; sP[90] = e2 / es;
        sP[91] = 1.0f + softplus_(sc[5]);
      } else if (tid >= 256 && tid < 512) { // e (256..383) / a (384..511)
        const int cc = tid + 12;            // combined col = 134 + cw, cw = tid-122
        float v = 0.f;
#pragma unroll
        for (int q = 0; q < 4; ++q) v += U[cc + 524 * q];
        v += bw[tid - 122];
        sOw[tid - 120] = (tid < 384) ? sigmoid_(v) : tanh_(v);
      } else if (tid >= 512 && tid < 640) { // k_w col cw (waves 8,9 whole): |k_w|^2
        const int cw = tid - 512;
        float v = 0.f;
#pragma unroll
        for (int q = 0; q < 4; ++q) v += U[(134 + cw) + 524 * q];
        v += bw[cw];
        sOw[cw] = v;
        float s2 = waveSum(v * v);
        if (lane == 0) atomicAdd(&sP[1], s2);
      } else if (tid >= 640 && tid < 768) {
        sR[tid - 640] = 0.f;                // Seg-9 ds_add target
      } else if (tid >= 768 && tid < 800) { // bf16 key packing from U (redundant combine)
        const int t2 = tid - 768;
        const int c = t2 & 15;
        union { uint4 v; unsigned short h[8]; } pk;
#pragma unroll
        for (int j = 0; j < 8; ++j) {
          const int col = c * 8 + j;        // 0..127
          float v = 0.f;
#pragma unroll
          for (int q = 0; q < 4; ++q)
            v += U[((t2 < 16) ? col : (134 + col)) + 524 * q];
          v += (t2 < 16) ? br[col] : bw[col];
          pk.h[j] = f2us(v);
        }
        if (t2 < 16) krP[c] = pk.v; else kwP[c] = pk.v;
      }
      __syncthreads();
    }

    // ==== Seg 6 (A): dots + norm + exp fused; bf16 keys; SR/SW via atomic ====
    {
      const float kn_r = sqrtf(sP[0]);
      const float kn_w = sqrtf(sP[1]);
      const float beta_r = sP[80], beta_w = sP[86];
      const int n = tid >> 1, hf = tid & 1;
      const int sw = (n >> 2) & 3;
      float dr = 0.f, dw = 0.f, ss = 0.f;
#pragma unroll
      for (int c = 0; c < 8; ++c) {
        const int cl = hf * 8 + c;
        const uint4 mv = memv[n * 16 + (cl ^ sw)];
        const uint4 kr = krP[cl];
        const uint4 kw = kwP[cl];
        const unsigned mw_[4] = { mv.x, mv.y, mv.z, mv.w };
        const unsigned krw[4] = { kr.x, kr.y, kr.z, kr.w };
        const unsigned kww[4] = { kw.x, kw.y, kw.z, kw.w };
#pragma unroll
        for (int j = 0; j < 4; ++j) {
          const float m0 = bf_lo(mw_[j]), m1 = bf_hi(mw_[j]);
          dr = fmaf(m0, bf_lo(krw[j]), dr); dr = fmaf(m1, bf_hi(krw[j]), dr);
          dw = fmaf(m0, bf_lo(kww[j]), dw); dw = fmaf(m1, bf_hi(kww[j]), dw);
          ss = fmaf(m0, m0, ss);            ss = fmaf(m1, m1, ss);
        }
      }
      dr += __shfl_xor(dr, 1);
      dw += __shfl_xor(dw, 1);
      ss += __shfl_xor(ss, 1);
      const float nr = sqrtf(ss);
      const float er = __expf(beta_r * dr / (nr * kn_r + EPSF));
      const float ew = __expf(beta_w * dw / (nr * kn_w + EPSF));
      if (hf == 0) { eR[n] = er; eW[n] = ew; }
      float s1 = waveSum(er) * 0.5f;
      float s2 = waveSum(ew) * 0.5f;
      if (lane == 0) { atomicAdd(&sP[2], s1); atomicAdd(&sP[3], s2); }
      __syncthreads();
    }

    // ==== Seg 7: alpha (tid<512) + Y-top GEMV rows 0..127 (upper waves) ====
    {
      if (tid < NSLOT) {
        const float invE = 1.0f / sP[2];
        const float gr = sP[81], omg = 1.0f - sP[81];
        const int im = (tid - 1) & 511, ip = (tid + 1) & 511;
        const float wgm = gr * (eR[im] * invE) + omg * sWprev[im];
        const float wg0 = gr * (eR[tid] * invE) + omg * sWprev[tid];
        const float wgp = gr * (eR[ip] * invE) + omg * sWprev[ip];
        const float wt = sP[82] * wgp + sP[83] * wg0 + sP[84] * wgm;
        float p1 = (wt > 0.0f) ? __expf(sP[85] * __logf(wt)) : 0.0f;
        float P = waveSum(p1);
        sP1[tid] = p1;
        if (lane == 0) atomicAdd(&sP[4], P);
      } else {
        const int p = tid - 512;
        const int j4 = (p & 31) * 4, sl = p >> 5;   // 16 segs x 8 rows (0..127)
        float4 acc = make_float4(0.f, 0.f, 0.f, 0.f);
#pragma unroll
        for (int w = 0; w < 8; ++w) {
          const float v = sH[8 * sl + w];
          const float4 wv = *(const float4*)(Wout + (8 * sl + w) * DIN + j4);
          acc.x = fmaf(v, wv.x, acc.x); acc.y = fmaf(v, wv.y, acc.y);
          acc.z = fmaf(v, wv.z, acc.z); acc.w = fmaf(v, wv.w, acc.w);
        }
        *(float4*)(yP + sl * 128 + j4) = acc;
      }
      __syncthreads();
    }
    // ==== Seg 8: beta (tid<512) + x prefetch (idle upper waves) ====
    {
      if (tid < NSLOT) {
        const float pinv1 = 1.0f / (sP[4] + EPSF);
        const float invE = 1.0f / sP[3];
        const float gw = sP[87], omg = 1.0f - sP[87];
        const int im = (tid - 1) & 511, ip = (tid + 1) & 511;
        const float wgm = gw * (eW[im] * invE) + omg * (sP1[im] * pinv1);
        const float wg0 = gw * (eW[tid] * invE) + omg * (sP1[tid] * pinv1);
        const float wgp = gw * (eW[ip] * invE) + omg * (sP1[ip] * pinv1);
        sWr[tid] = sP1[tid] * pinv1;
        const float wt = sP[88] * wgp + sP[89] * wg0 + sP[90] * wgm;
        float p2 = (wt > 0.0f) ? __expf(sP[91] * __logf(wt)) : 0.0f;
        float P = waveSum(p2);
        U[tid] = p2;                       // raw p2 (eR region, dead)
        if (lane == 0) atomicAdd(&sP[5], P);
      } else if (tid < 512 + DIN && t + 1 < TSTEPS) {
        const int i = tid - 512;
        sXt[i] = x[((size_t)b * TSTEPS + (t + 1)) * DIN + i];
      }
      __syncthreads();
    }

    // ==== Seg 9 (B): w_w inline; r-sweep + mem update; r via ds_add into sR ====
    {
      const float pinv2 = 1.0f / (sP[5] + EPSF);
      if (tid < NSLOT) sWprev[tid] = U[tid] * pinv2;   // next step's w_prev

      const int cl = l ^ ((g >> 2) & 3);
      float4 e4a = *(const float4*)(sOw + 136 + cl * 8);
      float4 e4b = *(const float4*)(sOw + 140 + cl * 8);
      float4 a4a = *(const float4*)(sOw + 264 + cl * 8);
      float4 a4b = *(const float4*)(sOw + 268 + cl * 8);
      const float e8[8] = { e4a.x, e4a.y, e4a.z, e4a.w, e4b.x, e4b.y, e4b.z, e4b.w };
      const float a8[8] = { a4a.x, a4a.y, a4a.z, a4a.w, a4b.x, a4b.y, a4b.z, a4b.w };
      float r8[8] = { 0, 0, 0, 0, 0, 0, 0, 0 };
#pragma unroll 2
      for (int it = 0; it < 8; ++it) {
        const int n = g + 64 * it;
        const float wrn = sWr[n];
        const float wwn = U[n] * pinv2;
        uint4 pk = memv[n * 16 + l];
        const unsigned wds[4] = { pk.x, pk.y, pk.z, pk.w };
        float m[8];
#pragma unroll
        for (int j = 0; j < 4; ++j) { m[2 * j] = bf_lo(wds[j]); m[2 * j + 1] = bf_hi(wds[j]); }
#pragma unroll
        for (int j = 0; j < 8; ++j) {
          r8[j] = fmaf(wrn, m[j], r8[j]);
          const float d = fmaf(-e8[j], m[j], a8[j]);
          m[j] = fmaf(wwn, d, m[j]);
        }
        pk.x = pkbf(m[0], m[1]);
        pk.y = pkbf(m[2], m[3]);
        pk.z = pkbf(m[4], m[5]);
        pk.w = pkbf(m[6], m[7]);
        memv[n * 16 + l] = pk;
      }
#pragma unroll
      for (int j = 0; j < 8; ++j) {          // partners g^1,g^2 share chunk
        r8[j] += __shfl_xor(r8[j], 16);
        r8[j] += __shfl_xor(r8[j], 32);
      }
      if (lane < 16) {                       // 16 waves x 8 ds_add into sR
#pragma unroll
        for (int j = 0; j < 8; ++j) atomicAdd(&sR[cl * 8 + j], r8[j]);
      }
      __syncthreads();
    }

    // ==== Seg 11: Y-bottom GEMV rows 128..255 (tid<512), accumulate into yP ====
    {
      if (tid < 512) {
        const int j4 = (tid & 31) * 4, sl = tid >> 5;   // 16 segs x 8 rows
        float4 acc = *(const float4*)(yP + sl * 128 + j4);
#pragma unroll
        for (int w = 0; w < 8; ++w) {
          const float v = sR[8 * sl + w];
          const float4 wv = *(const float4*)(Wout + (128 + 8 * sl + w) * DIN + j4);
          acc.x = fmaf(v, wv.x, acc.x); acc.y = fmaf(v, wv.y, acc.y);
          acc.z = fmaf(v, wv.z, acc.z); acc.w = fmaf(v, wv.w, acc.w);
        }
        *(float4*)(yP + sl * 128 + j4) = acc;
      }
      __syncthreads();
    }
  }

  // final y
  if (tid < DIN) {
    float y = bout[tid];
#pragma unroll
    for (int q = 0; q < 16; ++q) y += yP[q * 128 + tid];
    out[((size_t)b * TSTEPS + (TSTEPS - 1)) * DIN + tid] = y;
  }
}

extern "C" void kernel_launch(void* const* d_in, const int* in_sizes, int n_in,
                              void* d_out, int out_size, void* d_ws, size_t ws_size,
                              hipStream_t stream) {
  (void)in_sizes; (void)n_in; (void)out_size; (void)d_ws; (void)ws_size;
  hipFuncSetAttribute(reinterpret_cast<const void*>(ntm_kernel),
                      hipFuncAttributeMaxDynamicSharedMemorySize, (int)LDS_BYTES);
  ntm_kernel<<<dim3(BSZ), dim3(NT), LDS_BYTES, stream>>>(
      (const float*)d_in[0], (const float*)d_in[1], (const float*)d_in[2],
      (const float*)d_in[3], (const float*)d_in[4], (const float*)d_in[5],
      (const float*)d_in[6], (const float*)d_in[7], (const float*)d_in[8],
      (const float*)d_in[9], (const float*)d_in[10],
      (float*)d_out);
}

// Round 16
// 855.446 us; speedup vs baseline: 1.3647x; 1.0199x over previous
//
#include <hip/hip_runtime.h>
#include <hip/hip_bf16.h>
#include <math.h>

#define NT 1024
#define BSZ 128
#define TSTEPS 32
#define DIN 128
#define DHH 128
#define NSLOT 512
#define EPSF 1e-8f

// LDS: [0,131072) mem bf16[512][128] XOR-swizzled; then float scratch F[7160]
static constexpr int F_FLOATS = 7160;
static constexpr size_t LDS_BYTES = 131072 + F_FLOATS * sizeof(float);

__device__ __forceinline__ float bf_lo(unsigned u) {
  union { unsigned u; float f; } c; c.u = u << 16; return c.f;
}
__device__ __forceinline__ float bf_hi(unsigned u) {
  union { unsigned u; float f; } c; c.u = u & 0xffff0000u; return c.f;
}
__device__ __forceinline__ unsigned short f2us(float f) {
  union { unsigned short s; __hip_bfloat16 h; } c; c.h = __float2bfloat16(f); return c.s;
}
__device__ __forceinline__ unsigned pkbf(float a, float b) {
  union { __hip_bfloat162 h2; unsigned u; } c;
  c.h2 = __float22bfloat162_rn(make_float2(a, b));
  return c.u;
}
__device__ __forceinline__ float sigmoid_(float x) { return 1.0f / (1.0f + __expf(-x)); }
__device__ __forceinline__ float softplus_(float x) {
  return fmaxf(x, 0.0f) + log1pf(__expf(-fabsf(x)));
}
__device__ __forceinline__ float tanh_(float x) {
  float e = __expf(-2.0f * fabsf(x));
  float t = (1.0f - e) / (1.0f + e);
  return copysignf(t, x);
}
__device__ __forceinline__ float waveSum(float v) {
#pragma unroll
  for (int m = 32; m >= 1; m >>= 1) v += __shfl_xor(v, m);
  return v;
}

// One block (1024 threads) per batch element; all 32 steps in-block.
// mem in LDS, rows XOR-swizzled: stored uint4 slot u = c ^ ((n>>2)&3).
// Base = r15 (828us verified). Single-mechanism delta (long-pole balancing):
//   1. Seg 3's 24 extra slots split into 48 half-slots, 3 per wave (lanes 0-2)
//      -> every wave pays +0.5 slot instead of wave 0 paying +1.0. The q=3
//      partials for Ww cols 342..389 are stored at U[2096..2191] and combined
//      with 5 reads in SegF's a-branch.
//   2. y-finalize moved from Seg 1 (stacked on waves 0,1) to SegF's idle
//      threads 896..1023 (waves 14,15).
__global__ __launch_bounds__(NT, 4)
void ntm_kernel(const float* __restrict__ x,
                const float* __restrict__ Wxh,
                const float* __restrict__ Whh,
                const float* __restrict__ Wrh,
                const float* __restrict__ bh,
                const float* __restrict__ Wout,
                const float* __restrict__ bout,
                const float* __restrict__ Wr,
                const float* __restrict__ br,
                const float* __restrict__ Ww,
                const float* __restrict__ bw,
                float* __restrict__ out)
{
  extern __shared__ char smem[];
  uint4* memv = (uint4*)smem;              // bf16 mem, row n = 16 uint4 (swizzled)
  float* F = (float*)(smem + 131072);

  const int b = blockIdx.x;
  const int tid = threadIdx.x;
  const int g = tid >> 4, l = tid & 15;    // Phase-B mapping
  const int lane = tid & 63, wid = tid >> 6;

  float* U      = F + 0;      // 2560 multi-use: O/H partials (incl. [2096..2191]
                              //      half-slot partials); eR/eW; p2raw
  float* yP     = F + 2560;   // 2048 Y partials (live across step boundary)
  float* sWprev = F + 4608;   // 512
  float* sWr    = F + 5120;   // 512
  float* sP1    = F + 5632;   // 512 p1; aliased early by krP/kwP packed keys
  float* sOr    = F + 6144;   // 144 (134 used)
  float* sOw    = F + 6288;   // 392: [0..127] k_w, [136..263] e (16B-aligned), [264..391] a
  float* sH     = F + 6680;   // 128
  float* sR     = F + 6808;   // 128 (ds_add target in Seg 9)
  float* sXt    = F + 6936;   // 128
  float* sP     = F + 7064;   // 96: [0]kr2 [1]kw2 [2]SR [3]SW [4]P1 [5]P2; [80..91] scalars
  uint4* krP    = (uint4*)(sP1 + 0);
  uint4* kwP    = (uint4*)(sP1 + 64);
  float* eR     = U + 0;
  float* eW     = U + 512;

  // ---- init ----
  {
    const unsigned short mb = f2us(1e-6f);
    const unsigned w32 = ((unsigned)mb << 16) | mb;
    const uint4 fv = make_uint4(w32, w32, w32, w32);
    for (int i = tid; i < NSLOT * DHH / 8; i += NT) memv[i] = fv;
  }
  for (int i = tid; i < NSLOT; i += NT) sWprev[i] = 1.0f / NSLOT;
  if (tid < DHH) { sH[tid] = 0.0f; sR[tid] = 0.0f; }
  if (tid < DIN) sXt[tid] = x[(size_t)b * TSTEPS * DIN + tid];
  __syncthreads();

  for (int t = 0; t < TSTEPS; ++t) {
    // ==== Seg 1: H partials (float2 weights, LDS state reads) ====
    {
      const int q = tid & 63, s = tid >> 6;   // s == wid: wave-uniform rows
      const int j2 = q * 2, i0 = s * 24;
      float2 acc = make_float2(0.f, 0.f);
#pragma unroll 8
      for (int w = 0; w < 24; ++w) {
        const int i = i0 + w;
        float v; const float* Wp;
        if (i < 128)      { v = sXt[i];       Wp = Wxh + i * DHH; }
        else if (i < 256) { v = sH[i - 128];  Wp = Whh + (i - 128) * DHH; }
        else              { v = sR[i - 256];  Wp = Wrh + (i - 256) * DHH; }
        const float2 wv = *(const float2*)(Wp + j2);
        acc.x = fmaf(v, wv.x, acc.x);
        acc.y = fmaf(v, wv.y, acc.y);
      }
      *(float2*)(U + s * 128 + j2) = acc;
      __syncthreads();
    }
    // ==== Seg 2: h = tanh(sum + bh) ====
    if (tid < DHH) {
      float a2 = bh[tid];
#pragma unroll
      for (int q2 = 0; q2 < 16; ++q2) a2 += U[q2 * 128 + tid];
      sH[tid] = tanh_(a2);
    }
    __syncthreads();

    // ==== Seg 3: O partials — pass1 slot=tid; pass2 48 half-slots, 3/wave ====
    {
      {
        const int s = tid;                  // 0..1023 (all valid, < 1048)
        const int q = (s >= 786) ? 3 : (s >= 524) ? 2 : (s >= 262) ? 1 : 0;
        const int P = s - 262 * q;
        const int i0 = 32 * q;
        const float2* p;
        int strideF2;
        if (P < 67) { p = (const float2*)(Wr + i0 * 134 + 2 * P); strideF2 = 67; }
        else        { p = (const float2*)(Ww + i0 * 390 + 2 * (P - 67)); strideF2 = 195; }
        float2 acc = make_float2(0.f, 0.f);
#pragma unroll 8
        for (int w = 0; w < 32; ++w) {
          const float v = sH[i0 + w];
          const float2 wv = *p;
          acc.x = fmaf(v, wv.x, acc.x);
          acc.y = fmaf(v, wv.y, acc.y);
          p += strideF2;
        }
        *(float2*)(U + s * 2) = acc;
      }
      if (lane < 3) {                       // 48 half-slots: former slots 1024..1047
        const int hs = wid * 3 + lane;      // 0..47
        const int e = hs >> 1, hh = hs & 1;
        const int cp = 171 + e;             // Ww col-pair (P = 238+e >= 67)
        const int i0 = 96 + 16 * hh;
        const float2* p = (const float2*)(Ww + i0 * 390 + 2 * cp);
        float2 acc = make_float2(0.f, 0.f);
#pragma unroll 8
        for (int w = 0; w < 16; ++w) {
          const float v = sH[i0 + w];
          const float2 wv = *p;
          acc.x = fmaf(v, wv.x, acc.x);
          acc.y = fmaf(v, wv.y, acc.y);
          p += 195;
        }
        U[2096 + hs * 2]     = acc.x;
        U[2096 + hs * 2 + 1] = acc.y;
      }
      if (tid == 1023) {
        sP[0] = 0.f; sP[1] = 0.f; sP[2] = 0.f; sP[3] = 0.f; sP[4] = 0.f; sP[5] = 0.f;
      }
      __syncthreads();
    }

    // ==== Seg F: fused combine+bias / knorm / e,a transforms / key packing /
    //      head scalars / sR zeroing / y-finalize(t-1) ====
    {
      if (tid < 134) {                      // o_r col tid
        float v = 0.f;
#pragma unroll
        for (int q = 0; q < 4; ++q) v += U[tid + 524 * q];
        v += br[tid];
        sOr[tid] = v;
        if (tid < 128) {                    // waves 0,1 whole: |k_r|^2
          float s2 = waveSum(v * v);
          if (lane == 0) atomicAdd(&sP[0], s2);
        }
      } else if (tid == 134) {              // read-head scalars from U directly
        float sc[6];
#pragma unroll
        for (int j = 0; j < 6; ++j) {
          float v = 0.f;
#pragma unroll
          for (int q = 0; q < 4; ++q) v += U[(128 + j) + 524 * q];
          sc[j] = v + br[128 + j];
        }
        sP[80] = softplus_(sc[0]);
        sP[81] = sigmoid_(sc[1]);
        float mx = fmaxf(sc[2], fmaxf(sc[3], sc[4]));
        float e0 = __expf(sc[2] - mx), e1 = __expf(sc[3] - mx), e2 = __expf(sc[4] - mx);
        float es = e0 + e1 + e2;
        sP[82] = e0 / es; sP[83] = e1 / es; sP[84] = e2 / es;
        sP[85] = 1.0f + softplus_(sc[5]);
      } else if (tid == 135) {              // write-head scalars (o_w cols 128..133)
        float sc[6];
#pragma unroll
        for (int j = 0; j < 6; ++j) {
          float v = 0.f;
#pragma unroll
          for (int q = 0; q < 4; ++q) v += U[(262 + j) + 524 * q];
          sc[j] = v + bw[128 + j];
        }
        sP[86] = softplus_(sc[0]);
        sP[87] = sigmoid_(sc[1]);
        float mx = fmaxf(sc[2], fmaxf(sc[3], sc[4]));
        float e0 = __expf(sc[2] - mx), e1 = __expf(sc[3] - mx), e2 = __expf(sc[4] - mx);
        float es = e0 + e1 + e2;
        sP[88] = e0 / es; sP[89] = e1 / es; sP[90] = e2 / es;
        sP[91] = 1.0f + softplus_(sc[5]);
      } else if (tid >= 256 && tid < 512) { // e (256..383) / a (384..511)
        const int cc = tid + 12;            // combined col = 134 + cw, cw = tid-122
        float v = U[cc] + U[cc + 524] + U[cc + 1048];
        if (cc < 476) {
          v += U[cc + 1572];
        } else {                            // q=3 partial split into 2 halves
          const int cw = cc - 134;          // 342..389
          const int e = (cw >> 1) - 171;    // 0..23
          const int base = 2096 + 4 * e + (cw & 1);
          v += U[base] + U[base + 2];
        }
        v += bw[tid - 122];
        sOw[tid - 120] = (tid < 384) ? sigmoid_(v) : tanh_(v);
      } else if (tid >= 512 && tid < 640) { // k_w col cw (waves 8,9 whole): |k_w|^2
        const int cw = tid - 512;
        float v = 0.f;
#pragma unroll
        for (int q = 0; q < 4; ++q) v += U[(134 + cw) + 524 * q];
        v += bw[cw];
        sOw[cw] = v;
        float s2 = waveSum(v * v);
        if (lane == 0) atomicAdd(&sP[1], s2);
      } else if (tid >= 640 && tid < 768) {
        sR[tid - 640] = 0.f;                // Seg-9 ds_add target
      } else if (tid >= 768 && tid < 800) { // bf16 key packing from U (redundant combine)
        const int t2 = tid - 768;
        const int c = t2 & 15;
        union { uint4 v; unsigned short h[8]; } pk;
#pragma unroll
        for (int j = 0; j < 8; ++j) {
          const int col = c * 8 + j;        // 0..127
          float v = 0.f;
#pragma unroll
          for (int q = 0; q < 4; ++q)
            v += U[((t2 < 16) ? col : (134 + col)) + 524 * q];
          v += (t2 < 16) ? br[col] : bw[col];
          pk.h[j] = f2us(v);
        }
        if (t2 < 16) krP[c] = pk.v; else kwP[c] = pk.v;
      } else if (tid >= 896) {              // y-finalize(t-1) on idle waves 14,15
        if (t > 0) {
          const int c = tid - 896;
          float y = bout[c];
#pragma unroll
          for (int q = 0; q < 16; ++q) y += yP[q * 128 + c];
          out[((size_t)b * TSTEPS + (t - 1)) * DIN + c] = y;
        }
      }
      __syncthreads();
    }

    // ==== Seg 6 (A): dots + norm + exp fused; bf16 keys; SR/SW via atomic ====
    {
      const float kn_r = sqrtf(sP[0]);
      const float kn_w = sqrtf(sP[1]);
      const float beta_r = sP[80], beta_w = sP[86];
      const int n = tid >> 1, hf = tid & 1;
      const int sw = (n >> 2) & 3;
      float dr = 0.f, dw = 0.f, ss = 0.f;
#pragma unroll
      for (int c = 0; c < 8; ++c) {
        const int cl = hf * 8 + c;
        const uint4 mv = memv[n * 16 + (cl ^ sw)];
        const uint4 kr = krP[cl];
        const uint4 kw = kwP[cl];
        const unsigned mw_[4] = { mv.x, mv.y, mv.z, mv.w };
        const unsigned krw[4] = { kr.x, kr.y, kr.z, kr.w };
        const unsigned kww[4] = { kw.x, kw.y, kw.z, kw.w };
#pragma unroll
        for (int j = 0; j < 4; ++j) {
          const float m0 = bf_lo(mw_[j]), m1 = bf_hi(mw_[j]);
          dr = fmaf(m0, bf_lo(krw[j]), dr); dr = fmaf(m1, bf_hi(krw[j]), dr);
          dw = fmaf(m0, bf_lo(kww[j]), dw); dw = fmaf(m1, bf_hi(kww[j]), dw);
          ss = fmaf(m0, m0, ss);            ss = fmaf(m1, m1, ss);
        }
      }
      dr += __shfl_xor(dr, 1);
      dw += __shfl_xor(dw, 1);
      ss += __shfl_xor(ss, 1);
      const float nr = sqrtf(ss);
      const float er = __expf(beta_r * dr / (nr * kn_r + EPSF));
      const float ew = __expf(beta_w * dw / (nr * kn_w + EPSF));
      if (hf == 0) { eR[n] = er; eW[n] = ew; }
      float s1 = waveSum(er) * 0.5f;
      float s2 = waveSum(ew) * 0.5f;
      if (lane == 0) { atomicAdd(&sP[2], s1); atomicAdd(&sP[3], s2); }
      __syncthreads();
    }

    // ==== Seg 7: alpha (tid<512) + Y-top GEMV rows 0..127 (upper waves) ====
    {
      if (tid < NSLOT) {
        const float invE = 1.0f / sP[2];
        const float gr = sP[81], omg = 1.0f - sP[81];
        const int im = (tid - 1) & 511, ip = (tid + 1) & 511;
        const float wgm = gr * (eR[im] * invE) + omg * sWprev[im];
        const float wg0 = gr * (eR[tid] * invE) + omg * sWprev[tid];
        const float wgp = gr * (eR[ip] * invE) + omg * sWprev[ip];
        const float wt = sP[82] * wgp + sP[83] * wg0 + sP[84] * wgm;
        float p1 = (wt > 0.0f) ? __expf(sP[85] * __logf(wt)) : 0.0f;
        float P = waveSum(p1);
        sP1[tid] = p1;
        if (lane == 0) atomicAdd(&sP[4], P);
      } else {
        const int p = tid - 512;
        const int j4 = (p & 31) * 4, sl = p >> 5;   // 16 segs x 8 rows (0..127)
        float4 acc = make_float4(0.f, 0.f, 0.f, 0.f);
#pragma unroll
        for (int w = 0; w < 8; ++w) {
          const float v = sH[8 * sl + w];
          const float4 wv = *(const float4*)(Wout + (8 * sl + w) * DIN + j4);
          acc.x = fmaf(v, wv.x, acc.x); acc.y = fmaf(v, wv.y, acc.y);
          acc.z = fmaf(v, wv.z, acc.z); acc.w = fmaf(v, wv.w, acc.w);
        }
        *(float4*)(yP + sl * 128 + j4) = acc;
      }
      __syncthreads();
    }
    // ==== Seg 8: beta (tid<512) + x prefetch (idle upper waves) ====
    {
      if (tid < NSLOT) {
        const float pinv1 = 1.0f / (sP[4] + EPSF);
        const float invE = 1.0f / sP[3];
        const float gw = sP[87], omg = 1.0f - sP[87];
        const int im = (tid - 1) & 511, ip = (tid + 1) & 511;
        const float wgm = gw * (eW[im] * invE) + omg * (sP1[im] * pinv1);
        const float wg0 = gw * (eW[tid] * invE) + omg * (sP1[tid] * pinv1);
        const float wgp = gw * (eW[ip] * invE) + omg * (sP1[ip] * pinv1);
        sWr[tid] = sP1[tid] * pinv1;
        const float wt = sP[88] * wgp + sP[89] * wg0 + sP[90] * wgm;
        float p2 = (wt > 0.0f) ? __expf(sP[91] * __logf(wt)) : 0.0f;
        float P = waveSum(p2);
        U[tid] = p2;                       // raw p2 (eR region, dead)
        if (lane == 0) atomicAdd(&sP[5], P);
      } else if (tid < 512 + DIN && t + 1 < TSTEPS) {
        const int i = tid - 512;
        sXt[i] = x[((size_t)b * TSTEPS + (t + 1)) * DIN + i];
      }
      __syncthreads();
    }

    // ==== Seg 9 (B): w_w inline; r-sweep + mem update; r via ds_add into sR ====
    {
      const float pinv2 = 1.0f / (sP[5] + EPSF);
      if (tid < NSLOT) sWprev[tid] = U[tid] * pinv2;   // next step's w_prev

      const int cl = l ^ ((g >> 2) & 3);
      float4 e4a = *(const float4*)(sOw + 136 + cl * 8);
      float4 e4b = *(const float4*)(sOw + 140 + cl * 8);
      float4 a4a = *(const float4*)(sOw + 264 + cl * 8);
      float4 a4b = *(const float4*)(sOw + 268 + cl * 8);
      const float e8[8] = { e4a.x, e4a.y, e4a.z, e4a.w, e4b.x, e4b.y, e4b.z, e4b.w };
      const float a8[8] = { a4a.x, a4a.y, a4a.z, a4a.w, a4b.x, a4b.y, a4b.z, a4b.w };
      float r8[8] = { 0, 0, 0, 0, 0, 0, 0, 0 };
#pragma unroll 2
      for (int it = 0; it < 8; ++it) {
        const int n = g + 64 * it;
        const float wrn = sWr[n];
        const float wwn = U[n] * pinv2;
        uint4 pk = memv[n * 16 + l];
        const unsigned wds[4] = { pk.x, pk.y, pk.z, pk.w };
        float m[8];
#pragma unroll
        for (int j = 0; j < 4; ++j) { m[2 * j] = bf_lo(wds[j]); m[2 * j + 1] = bf_hi(wds[j]); }
#pragma unroll
        for (int j = 0; j < 8; ++j) {
          r8[j] = fmaf(wrn, m[j], r8[j]);
          const float d = fmaf(-e8[j], m[j], a8[j]);
          m[j] = fmaf(wwn, d, m[j]);
        }
        pk.x = pkbf(m[0], m[1]);
        pk.y = pkbf(m[2], m[3]);
        pk.z = pkbf(m[4], m[5]);
        pk.w = pkbf(m[6], m[7]);
        memv[n * 16 + l] = pk;
      }
#pragma unroll
      for (int j = 0; j < 8; ++j) {          // partners g^1,g^2 share chunk
        r8[j] += __shfl_xor(r8[j], 16);
        r8[j] += __shfl_xor(r8[j], 32);
      }
      if (lane < 16) {                       // 16 waves x 8 ds_add into sR
#pragma unroll
        for (int j = 0; j < 8; ++j) atomicAdd(&sR[cl * 8 + j], r8[j]);
      }
      __syncthreads();
    }

    // ==== Seg 11: Y-bottom GEMV rows 128..255 (tid<512), accumulate into yP ====
    {
      if (tid < 512) {
        const int j4 = (tid & 31) * 4, sl = tid >> 5;   // 16 segs x 8 rows
        float4 acc = *(const float4*)(yP + sl * 128 + j4);
#pragma unroll
        for (int w = 0; w < 8; ++w) {
          const float v = sR[8 * sl + w];
          const float4 wv = *(const float4*)(Wout + (128 + 8 * sl + w) * DIN + j4);
          acc.x = fmaf(v, wv.x, acc.x); acc.y = fmaf(v, wv.y, acc.y);
          acc.z = fmaf(v, wv.z, acc.z); acc.w = fmaf(v, wv.w, acc.w);
        }
        *(float4*)(yP + sl * 128 + j4) = acc;
      }
      __syncthreads();
    }
  }

  // final y
  if (tid < DIN) {
    float y = bout[tid];
#pragma unroll
    for (int q = 0; q < 16; ++q) y += yP[q * 128 + tid];
    out[((size_t)b * TSTEPS + (TSTEPS - 1)) * DIN + tid] = y;
  }
}

extern "C" void kernel_launch(void* const* d_in, const int* in_sizes, int n_in,
                              void* d_out, int out_size, void* d_ws, size_t ws_size,
                              hipStream_t stream) {
  (void)in_sizes; (void)n_in; (void)out_size; (void)d_ws; (void)ws_size;
  hipFuncSetAttribute(reinterpret_cast<const void*>(ntm_kernel),
                      hipFuncAttributeMaxDynamicSharedMemorySize, (int)LDS_BYTES);
  ntm_kernel<<<dim3(BSZ), dim3(NT), LDS_BYTES, stream>>>(
      (const float*)d_in[0], (const float*)d_in[1], (const float*)d_in[2],
      (const float*)d_in[3], (const float*)d_in[4], (const float*)d_in[5],
      (const float*)d_in[6], (const float*)d_in[7], (const float*)d_in[8],
      (const float*)d_in[9], (const float*)d_in[10],
      (float*)d_out);
}